// Round 1
// baseline (537.589 us; speedup 1.0000x reference)
//
#include <hip/hip_runtime.h>
#include <cstdint>
#include <cstddef>

typedef unsigned short u16x8 __attribute__((ext_vector_type(8)));
typedef unsigned short u16x4 __attribute__((ext_vector_type(4)));
typedef __bf16 bf16x8 __attribute__((ext_vector_type(8)));
typedef float f32x4 __attribute__((ext_vector_type(4)));

__device__ __forceinline__ float b2f(unsigned short u) {
    union { unsigned int i; float f; } v;
    v.i = ((unsigned int)u) << 16;
    return v.f;
}

__device__ __forceinline__ unsigned short f2b(float f) {
    union { float f; unsigned int i; } v;
    v.f = f;
    unsigned int x = v.i;
    unsigned int lsb = (x >> 16) & 1u;
    x += 0x7FFFu + lsb;           // round-to-nearest-even
    return (unsigned short)(x >> 16);
}

__device__ __forceinline__ float gelu_exact(float x) {
    return 0.5f * x * (1.0f + erff(x * 0.70710678118654752f));
}

// async 16B global -> LDS (DMA). lds base is wave-uniform; lane i lands at
// base + i*16 bytes. [m97: global_load_lds_dwordx4]
__device__ __forceinline__ void ld_lds16(const unsigned short* g, unsigned short* l) {
    __builtin_amdgcn_global_load_lds(
        (const __attribute__((address_space(1))) void*)g,
        (__attribute__((address_space(3))) void*)l, 16, 0, 0);
}

// ---------------------------------------------------------------------------
// Transpose + cast (+ optional per-input-row scale): in is R x C row-major
// fp32, out is C x R row-major bf16, out[c][r] = in[r][c] * scale[r].
// ---------------------------------------------------------------------------
__global__ void transpose_f32_bf16(const float* __restrict__ in,
                                   unsigned short* __restrict__ out, int R, int C,
                                   const float* __restrict__ scale) {
    __shared__ float tile[32][33];
    int x = blockIdx.x * 32 + threadIdx.x;
    int y0 = blockIdx.y * 32;
    for (int k = 0; k < 32; k += 8)
        tile[threadIdx.y + k][threadIdx.x] = in[(size_t)(y0 + threadIdx.y + k) * C + x];
    __syncthreads();
    int ox = y0 + threadIdx.x;          // input row index
    int oy = blockIdx.x * 32;
    float sc = scale ? scale[ox] : 1.0f;
    for (int k = 0; k < 32; k += 8)
        out[(size_t)(oy + threadIdx.y + k) * R + ox] = f2b(tile[threadIdx.x][threadIdx.y + k] * sc);
}

__global__ void concat_bias(const float* __restrict__ b0, const float* __restrict__ b1,
                            float* __restrict__ out) {
    int t = threadIdx.x + blockIdx.x * blockDim.x;
    if (t < 256) out[t] = b0[t];
    else if (t < 768) out[t] = b1[t - 256];
}

__global__ void fzero(float* __restrict__ p, int n) {
    int i = blockIdx.x * 256 + threadIdx.x;
    if (i < n) p[i] = 0.0f;
}

// c0b2[n] = b2[n] (atomic target init), c1[n] = 0
__global__ void init_c01(const float* __restrict__ b2, float* __restrict__ c0b2,
                         float* __restrict__ c1) {
    int n = blockIdx.x * 256 + threadIdx.x;
    c0b2[n] = b2[n];
    c1[n] = 0.0f;
}

// c0b2[n] += sum_k b[k]*W2[k][n];  c1[n] += sum_k g[k]*W2[k][n]
// grid (N/256, K/256), 256 threads; W2 is K x N row-major fp32.
__global__ void prep_c01(const float* __restrict__ W2, const float* __restrict__ g,
                         const float* __restrict__ b, float* __restrict__ c0b2,
                         float* __restrict__ c1, int K, int N) {
    int n = blockIdx.x * 256 + threadIdx.x;
    int k0 = blockIdx.y * 256;
    float p0 = 0.f, p1 = 0.f;
    for (int k = k0; k < k0 + 256; ++k) {
        float w = W2[(size_t)k * N + n];
        p0 += b[k] * w;
        p1 += g[k] * w;
    }
    atomicAdd(&c0b2[n], p0);
    atomicAdd(&c1[n], p1);
}

// stats[2r]=sum, stats[2r+1]=sumsq  ->  stats[2r]=rs, stats[2r+1]=rs*mu
__global__ void ln_finalize(float* __restrict__ st, int n, float inv) {
    int r = blockIdx.x * 256 + threadIdx.x;
    if (r < n) {
        float mu = st[2 * r] * inv;
        float var = st[2 * r + 1] * inv - mu * mu;
        float rs = rsqrtf(var + 1e-5f);
        st[2 * r] = rs;
        st[2 * r + 1] = rs * mu;
    }
}

// ---------------------------------------------------------------------------
// LayerNorm over 1024 fp32 cols -> bf16, fully vectorized (float4 in, 8B out).
// ---------------------------------------------------------------------------
__global__ __launch_bounds__(256) void ln1024(const float* __restrict__ in,
                                              unsigned short* __restrict__ out,
                                              const float* __restrict__ g,
                                              const float* __restrict__ b) {
    const int row = blockIdx.x;
    const int t = threadIdx.x;
    f32x4 v = ((const f32x4*)(in + (size_t)row * 1024))[t];
    float s = v[0] + v[1] + v[2] + v[3];
    float s2 = v[0] * v[0] + v[1] * v[1] + v[2] * v[2] + v[3] * v[3];
#pragma unroll
    for (int o = 32; o > 0; o >>= 1) {
        s  += __shfl_down(s, o, 64);
        s2 += __shfl_down(s2, o, 64);
    }
    __shared__ float red[8];
    int lane = t & 63, w = t >> 6;
    if (lane == 0) { red[w] = s; red[4 + w] = s2; }
    __syncthreads();
    if (t == 0) {
        red[0] = red[0] + red[1] + red[2] + red[3];
        red[4] = red[4] + red[5] + red[6] + red[7];
    }
    __syncthreads();
    const float inv_n = 1.0f / 1024.0f;
    float mu = red[0] * inv_n;
    float var = red[4] * inv_n - mu * mu;
    float rs = rsqrtf(var + 1e-5f);
    f32x4 gv = ((const f32x4*)g)[t];
    f32x4 bv = ((const f32x4*)b)[t];
    u16x4 ov;
#pragma unroll
    for (int r = 0; r < 4; ++r) ov[r] = f2b((v[r] - mu) * rs * gv[r] + bv[r]);
    ((u16x4*)(out + (size_t)row * 1024))[t] = ov;
}

// ---------------------------------------------------------------------------
// GEMM: epi(A[M x K] * BT[N x K]^T + bias). A,BT bf16 (row strides lda/ldb);
// fp32 acc. Tile 128x128x32; 256 threads = 4 waves, each 64x64.
// Double-buffered LDS + single barrier per iter; XOR-swizzled staging.
// XCD-aware bijective block swizzle (T1): all launch grids here are %8==0.
// EPI: 0 = bias + exact GELU -> bf16 Cb
//      3 = EPI 0 + per-row sum/sumsq of gelu output atomically into Cf[2*row]
//      1 = bias -> bf16 Cb only where idx[row] == match
//      2 = folded-LN epilogue:
//          Cf = (rs*acc + c0b2[col] - rsmu*c1[col]) * wm + adaptive_sel*(1-wm)
// ---------------------------------------------------------------------------
template <int EPI>
__global__ __launch_bounds__(256) void gemm_bt(
    const unsigned short* __restrict__ A, int lda,
    const unsigned short* __restrict__ BT, int ldb,
    const float* __restrict__ bias, unsigned short* __restrict__ Cb,
    float* __restrict__ Cf, int M, int N, int K,
    const int* __restrict__ idx, int match,
    const float* __restrict__ wm,
    const unsigned short* __restrict__ adaptive,
    const unsigned short* __restrict__ xn,
    const float* __restrict__ c1v,
    const float* __restrict__ rstat) {
    __shared__ __align__(16) unsigned short As[2][128 * 32];
    __shared__ __align__(16) unsigned short Bs[2][128 * 32];

    const int t = threadIdx.x;

    // XCD-aware bijective remap of the flattened block id (m157/m204).
    int id = blockIdx.y * gridDim.x + blockIdx.x;
    const int nwg = gridDim.x * gridDim.y;
    if ((nwg & 7) == 0) {
        const int cpx = nwg >> 3;
        id = (id & 7) * cpx + (id >> 3);
    }
    const int bx = id % gridDim.x;
    const int by = id / gridDim.x;
    const int m0 = by * 128;
    const int n0 = bx * 128;

    const int lane = t & 63;
    const int wid = t >> 6;

    // staging: lane i covers LDS rel-row i/4, chunk i%4; source column-chunk
    // is XOR-swizzled by row so readers land conflict-light.
    const int srow = lane >> 2;
    const int sch  = (lane & 3) ^ (srow & 3);   // source chunk (global col/8)
    const int scol = sch << 3;

    const int wr = (wid >> 1) << 6;
    const int wc = (wid & 1) << 6;
    const int ml = lane & 15;
    const int q = lane >> 4;
    const int qsw = ((q ^ (ml & 3)) << 3);      // swizzled LDS element offset

    f32x4 acc[4][4];
#pragma unroll
    for (int i = 0; i < 4; ++i)
#pragma unroll
        for (int j = 0; j < 4; ++j)
#pragma unroll
            for (int r = 0; r < 4; ++r) acc[i][j][r] = 0.0f;

    const int nk = K >> 5;

#define STAGE(KT, BUF)                                                          \
    {                                                                           \
        _Pragma("unroll")                                                       \
        for (int hh = 0; hh < 2; ++hh) {                                        \
            int rbase = wid * 32 + hh * 16;                                     \
            int row = rbase + srow;                                             \
            ld_lds16(A  + (size_t)(m0 + row) * lda + (KT) * 32 + scol,          \
                     &As[BUF][rbase * 32]);                                     \
            ld_lds16(BT + (size_t)(n0 + row) * ldb + (KT) * 32 + scol,          \
                     &Bs[BUF][rbase * 32]);                                     \
        }                                                                       \
    }

    STAGE(0, 0);
    for (int kt = 0; kt < nk; ++kt) {
        const int cur = kt & 1;
        __syncthreads();                 // drains DMA(kt) (in flight since kt-1)
        if (kt + 1 < nk) STAGE(kt + 1, cur ^ 1);

        bf16x8 af[4], bf[4];
#pragma unroll
        for (int i = 0; i < 4; ++i)
            af[i] = *(const bf16x8*)(&As[cur][(wr + i * 16 + ml) * 32 + qsw]);
#pragma unroll
        for (int j = 0; j < 4; ++j)
            bf[j] = *(const bf16x8*)(&Bs[cur][(wc + j * 16 + ml) * 32 + qsw]);
#pragma unroll
        for (int i = 0; i < 4; ++i)
#pragma unroll
            for (int j = 0; j < 4; ++j)
                acc[i][j] = __builtin_amdgcn_mfma_f32_16x16x32_bf16(af[i], bf[j], acc[i][j], 0, 0, 0);
    }
#undef STAGE

    // C/D layout: col = lane&15, row = quad*4 + reg  [m89/m91-verified]
#pragma unroll
    for (int i = 0; i < 4; ++i) {
        float rsum[4], rqs[4];
        float rsv[4], rmv[4], wv[4];
        int idv[4];
        if (EPI == 3) {
#pragma unroll
            for (int r = 0; r < 4; ++r) { rsum[r] = 0.f; rqs[r] = 0.f; }
        }
        if (EPI == 1 || EPI == 2) {
#pragma unroll
            for (int r = 0; r < 4; ++r) {
                int row = m0 + wr + i * 16 + q * 4 + r;
                idv[r] = idx[row];
                if (EPI == 2) {
                    wv[r] = wm[row];
                    rsv[r] = rstat[2 * (size_t)row];
                    rmv[r] = rstat[2 * (size_t)row + 1];
                }
            }
        }
#pragma unroll
        for (int j = 0; j < 4; ++j) {
            int col = n0 + wc + j * 16 + ml;
            float bv = bias[col];
            float c1c = (EPI == 2) ? c1v[col] : 0.0f;
#pragma unroll
            for (int r = 0; r < 4; ++r) {
                int row = m0 + wr + i * 16 + q * 4 + r;
                size_t off = (size_t)row * N + col;
                if (EPI == 0) {
                    Cb[off] = f2b(gelu_exact(acc[i][j][r] + bv));
                } else if (EPI == 3) {
                    float gv2 = gelu_exact(acc[i][j][r] + bv);
                    Cb[off] = f2b(gv2);
                    rsum[r] += gv2;
                    rqs[r] += gv2 * gv2;
                } else if (EPI == 1) {
                    if (idv[r] == match) Cb[off] = f2b(acc[i][j][r] + bv);
                } else {
                    float bval = rsv[r] * acc[i][j][r] + bv - rmv[r] * c1c;
                    float a = b2f((idv[r] <= 1) ? adaptive[off] : xn[off]);
                    Cf[off] = bval * wv[r] + a * (1.0f - wv[r]);
                }
            }
        }
        if (EPI == 3) {
            // reduce over the 16 cols held by lanes sharing this q-group,
            // then over j already done in-register; 2 atomics per row-half.
#pragma unroll
            for (int r = 0; r < 4; ++r) {
                float s = rsum[r], s2 = rqs[r];
                s  += __shfl_xor(s, 1);  s2 += __shfl_xor(s2, 1);
                s  += __shfl_xor(s, 2);  s2 += __shfl_xor(s2, 2);
                s  += __shfl_xor(s, 4);  s2 += __shfl_xor(s2, 4);
                s  += __shfl_xor(s, 8);  s2 += __shfl_xor(s2, 8);
                if (ml == 0) {
                    int row = m0 + wr + i * 16 + q * 4 + r;
                    atomicAdd(&Cf[2 * (size_t)row], s);
                    atomicAdd(&Cf[2 * (size_t)row + 1], s2);
                }
            }
        }
    }
}

// ---------------------------------------------------------------------------
extern "C" void kernel_launch(void* const* d_in, const int* in_sizes, int n_in,
                              void* d_out, int out_size, void* d_ws, size_t ws_size,
                              hipStream_t stream) {
    const float* x       = (const float*)d_in[0];
    const float* wm      = (const float*)d_in[1];
    const int*   widx    = (const int*)d_in[2];
    const float* ln_in_g = (const float*)d_in[3];
    const float* ln_in_b = (const float*)d_in[4];
    const float* W1      = (const float*)d_in[5];
    const float* b1      = (const float*)d_in[6];
    const float* ln_h_g  = (const float*)d_in[7];
    const float* ln_h_b  = (const float*)d_in[8];
    const float* W2      = (const float*)d_in[9];
    const float* b2      = (const float*)d_in[10];
    const float* a256_w1 = (const float*)d_in[11];
    const float* a256_b1 = (const float*)d_in[12];
    const float* a256_w2 = (const float*)d_in[13];
    const float* a256_b2 = (const float*)d_in[14];
    const float* a512_w1 = (const float*)d_in[15];
    const float* a512_b1 = (const float*)d_in[16];
    const float* a512_w2 = (const float*)d_in[17];
    const float* a512_b2 = (const float*)d_in[18];
    float* out = (float*)d_out;

    const int T = 8192, H = 1024, F = 4096;

    unsigned short* ws0   = (unsigned short*)d_ws;
    unsigned short* xn    = ws0;                       // T*H      bf16
    unsigned short* h     = xn    + (size_t)T * H;     // T*F      bf16
    unsigned short* tt    = h     + (size_t)T * F;     // T*768    bf16 (adapter ups, concat)
    unsigned short* adp   = tt    + (size_t)T * 768;   // T*H      bf16
    unsigned short* W1T   = adp   + (size_t)T * H;     // F*H      bf16
    unsigned short* W2T   = W1T   + (size_t)H * F;     // H*F      bf16 (pre-scaled by ln_h_g)
    unsigned short* awup  = W2T   + (size_t)F * H;     // 768*1024 bf16 (a256_w1^T ; a512_w1^T)
    unsigned short* aw2T0 = awup  + (size_t)768 * H;   // 1024*256 bf16
    unsigned short* aw2T1 = aw2T0 + (size_t)H * 256;   // 1024*512 bf16
    float*          ab1   = (float*)(aw2T1 + (size_t)H * 512);  // 768 fp32
    float*          stats = ab1 + 768;                 // T*2 fp32: sum/sumsq -> rs/rs*mu
    float*          c0b2  = stats + (size_t)T * 2;     // H fp32: b.W2 + b2
    float*          c1    = c0b2 + H;                  // H fp32: g.W2

    dim3 tb(32, 8);
    // LN-fold prep: W2T = (diag(g) W2)^T; c0b2 = b.W2 + b2; c1 = g.W2
    fzero<<<(2 * T + 255) / 256, 256, 0, stream>>>(stats, 2 * T);
    init_c01<<<H / 256, 256, 0, stream>>>(b2, c0b2, c1);
    prep_c01<<<dim3(H / 256, F / 256), 256, 0, stream>>>(W2, ln_h_g, ln_h_b, c0b2, c1, F, H);

    transpose_f32_bf16<<<dim3(F / 32,   H / 32), tb, 0, stream>>>(W1, W1T, H, F, nullptr);
    transpose_f32_bf16<<<dim3(H / 32,   F / 32), tb, 0, stream>>>(W2, W2T, F, H, ln_h_g);
    transpose_f32_bf16<<<dim3(256 / 32, H / 32), tb, 0, stream>>>(a256_w1, awup, H, 256, nullptr);
    transpose_f32_bf16<<<dim3(512 / 32, H / 32), tb, 0, stream>>>(a512_w1, awup + (size_t)256 * H, H, 512, nullptr);
    transpose_f32_bf16<<<dim3(H / 32, 256 / 32), tb, 0, stream>>>(a256_w2, aw2T0, 256, H, nullptr);
    transpose_f32_bf16<<<dim3(H / 32, 512 / 32), tb, 0, stream>>>(a512_w2, aw2T1, 512, H, nullptr);
    concat_bias<<<3, 256, 0, stream>>>(a256_b1, a512_b1, ab1);

    // x (fp32) -> x_norm (bf16), vectorized
    ln1024<<<T, 256, 0, stream>>>(x, xn, ln_in_g, ln_in_b);

    // base FFN up: h = gelu(xn @ W1 + b1), plus per-row sum/sumsq of h
    gemm_bt<3><<<dim3(F / 128, T / 128), 256, 0, stream>>>(
        xn, H, W1T, H, b1, h, stats, T, F, H, nullptr, 0, nullptr, nullptr, nullptr, nullptr, nullptr);

    // merged adapter ups: tt = gelu(xn @ [a256_w1 | a512_w1] + [b1|b1])
    gemm_bt<0><<<dim3(768 / 128, T / 128), 256, 0, stream>>>(
        xn, H, awup, H, ab1, tt, nullptr, T, 768, H, nullptr, 0, nullptr, nullptr, nullptr, nullptr, nullptr);

    // adapter downs (routed rows only)
    gemm_bt<1><<<dim3(H / 128, T / 128), 256, 0, stream>>>(
        tt, 768, aw2T0, 256, a256_b2, adp, nullptr, T, H, 256, widx, 0, nullptr, nullptr, nullptr, nullptr, nullptr);
    gemm_bt<1><<<dim3(H / 128, T / 128), 256, 0, stream>>>(
        tt + 256, 768, aw2T1, 512, a512_b2, adp, nullptr, T, H, 512, widx, 1, nullptr, nullptr, nullptr, nullptr, nullptr);

    // stats -> rs, rs*mu (in place); replaces the full LN pass over h
    ln_finalize<<<(T + 255) / 256, 256, 0, stream>>>(stats, T, 1.0f / (float)F);

    // out = (rs*(h @ g.W2) + (b.W2 + b2) - rs*mu*c1) * wm + adaptive * (1 - wm)
    gemm_bt<2><<<dim3(H / 128, T / 128), 256, 0, stream>>>(
        h, F, W2T, F, c0b2, nullptr, out, T, H, F, widx, 0, wm, adp, xn, c1, stats);
}

// Round 2
// 460.582 us; speedup vs baseline: 1.1672x; 1.1672x over previous
//
#include <hip/hip_runtime.h>
#include <cstdint>
#include <cstddef>

typedef unsigned short u16x8 __attribute__((ext_vector_type(8)));
typedef unsigned short u16x4 __attribute__((ext_vector_type(4)));
typedef __bf16 bf16x8 __attribute__((ext_vector_type(8)));
typedef float f32x4 __attribute__((ext_vector_type(4)));

__device__ __forceinline__ float b2f(unsigned short u) {
    union { unsigned int i; float f; } v;
    v.i = ((unsigned int)u) << 16;
    return v.f;
}

__device__ __forceinline__ unsigned short f2b(float f) {
    union { float f; unsigned int i; } v;
    v.f = f;
    unsigned int x = v.i;
    unsigned int lsb = (x >> 16) & 1u;
    x += 0x7FFFu + lsb;           // round-to-nearest-even
    return (unsigned short)(x >> 16);
}

__device__ __forceinline__ float gelu_exact(float x) {
    return 0.5f * x * (1.0f + erff(x * 0.70710678118654752f));
}

// async 16B global -> LDS (DMA). lds base is wave-uniform; lane i lands at
// base + i*16 bytes. [m97: global_load_lds_dwordx4]
__device__ __forceinline__ void ld_lds16(const unsigned short* g, unsigned short* l) {
    __builtin_amdgcn_global_load_lds(
        (const __attribute__((address_space(1))) void*)g,
        (__attribute__((address_space(3))) void*)l, 16, 0, 0);
}

// ---------------------------------------------------------------------------
// Transpose + cast (+ optional per-input-row scale): in is R x C row-major
// fp32, out is C x R row-major bf16, out[c][r] = in[r][c] * scale[r].
// ---------------------------------------------------------------------------
__global__ void transpose_f32_bf16(const float* __restrict__ in,
                                   unsigned short* __restrict__ out, int R, int C,
                                   const float* __restrict__ scale) {
    __shared__ float tile[32][33];
    int x = blockIdx.x * 32 + threadIdx.x;
    int y0 = blockIdx.y * 32;
    for (int k = 0; k < 32; k += 8)
        tile[threadIdx.y + k][threadIdx.x] = in[(size_t)(y0 + threadIdx.y + k) * C + x];
    __syncthreads();
    int ox = y0 + threadIdx.x;          // input row index
    int oy = blockIdx.x * 32;
    float sc = scale ? scale[ox] : 1.0f;
    for (int k = 0; k < 32; k += 8)
        out[(size_t)(oy + threadIdx.y + k) * R + ox] = f2b(tile[threadIdx.x][threadIdx.y + k] * sc);
}

__global__ void concat_bias(const float* __restrict__ b0, const float* __restrict__ b1,
                            float* __restrict__ out) {
    int t = threadIdx.x + blockIdx.x * blockDim.x;
    if (t < 256) out[t] = b0[t];
    else if (t < 768) out[t] = b1[t - 256];
}

// c0b2[n] = b2[n] (atomic target init), c1[n] = 0
__global__ void init_c01(const float* __restrict__ b2, float* __restrict__ c0b2,
                         float* __restrict__ c1) {
    int n = blockIdx.x * 256 + threadIdx.x;
    c0b2[n] = b2[n];
    c1[n] = 0.0f;
}

// c0b2[n] += sum_k b[k]*W2[k][n];  c1[n] += sum_k g[k]*W2[k][n]
// grid (N/256, K/256), 256 threads; W2 is K x N row-major fp32.
__global__ void prep_c01(const float* __restrict__ W2, const float* __restrict__ g,
                         const float* __restrict__ b, float* __restrict__ c0b2,
                         float* __restrict__ c1, int K, int N) {
    int n = blockIdx.x * 256 + threadIdx.x;
    int k0 = blockIdx.y * 256;
    float p0 = 0.f, p1 = 0.f;
    for (int k = k0; k < k0 + 256; ++k) {
        float w = W2[(size_t)k * N + n];
        p0 += b[k] * w;
        p1 += g[k] * w;
    }
    atomicAdd(&c0b2[n], p0);
    atomicAdd(&c1[n], p1);
}

// ---------------------------------------------------------------------------
// Per-row LN stats over 4096 bf16 cols: st[2r] = rs, st[2r+1] = rs*mu.
// One block per row, u16x8 vectorized loads, no atomics.
// ---------------------------------------------------------------------------
__global__ __launch_bounds__(256) void rowstats4096(const unsigned short* __restrict__ h,
                                                    float* __restrict__ st) {
    const int row = blockIdx.x;
    const int t = threadIdx.x;
    const u16x8* p = (const u16x8*)(h + (size_t)row * 4096);
    float s = 0.f, s2 = 0.f;
#pragma unroll
    for (int i = 0; i < 2; ++i) {
        u16x8 v = p[t + (i << 8)];
#pragma unroll
        for (int r = 0; r < 8; ++r) { float f = b2f(v[r]); s += f; s2 += f * f; }
    }
#pragma unroll
    for (int o = 32; o > 0; o >>= 1) {
        s  += __shfl_down(s, o, 64);
        s2 += __shfl_down(s2, o, 64);
    }
    __shared__ float red[8];
    int lane = t & 63, w = t >> 6;
    if (lane == 0) { red[w] = s; red[4 + w] = s2; }
    __syncthreads();
    if (t == 0) {
        float ss = red[0] + red[1] + red[2] + red[3];
        float qq = red[4] + red[5] + red[6] + red[7];
        const float inv = 1.0f / 4096.0f;
        float mu = ss * inv;
        float var = qq * inv - mu * mu;
        float rs = rsqrtf(var + 1e-5f);
        st[2 * (size_t)row]     = rs;
        st[2 * (size_t)row + 1] = rs * mu;
    }
}

// ---------------------------------------------------------------------------
// LayerNorm over 1024 fp32 cols -> bf16, fully vectorized (float4 in, 8B out).
// ---------------------------------------------------------------------------
__global__ __launch_bounds__(256) void ln1024(const float* __restrict__ in,
                                              unsigned short* __restrict__ out,
                                              const float* __restrict__ g,
                                              const float* __restrict__ b) {
    const int row = blockIdx.x;
    const int t = threadIdx.x;
    f32x4 v = ((const f32x4*)(in + (size_t)row * 1024))[t];
    float s = v[0] + v[1] + v[2] + v[3];
    float s2 = v[0] * v[0] + v[1] * v[1] + v[2] * v[2] + v[3] * v[3];
#pragma unroll
    for (int o = 32; o > 0; o >>= 1) {
        s  += __shfl_down(s, o, 64);
        s2 += __shfl_down(s2, o, 64);
    }
    __shared__ float red[8];
    int lane = t & 63, w = t >> 6;
    if (lane == 0) { red[w] = s; red[4 + w] = s2; }
    __syncthreads();
    if (t == 0) {
        red[0] = red[0] + red[1] + red[2] + red[3];
        red[4] = red[4] + red[5] + red[6] + red[7];
    }
    __syncthreads();
    const float inv_n = 1.0f / 1024.0f;
    float mu = red[0] * inv_n;
    float var = red[4] * inv_n - mu * mu;
    float rs = rsqrtf(var + 1e-5f);
    f32x4 gv = ((const f32x4*)g)[t];
    f32x4 bv = ((const f32x4*)b)[t];
    u16x4 ov;
#pragma unroll
    for (int r = 0; r < 4; ++r) ov[r] = f2b((v[r] - mu) * rs * gv[r] + bv[r]);
    ((u16x4*)(out + (size_t)row * 1024))[t] = ov;
}

// ---------------------------------------------------------------------------
// GEMM: epi(A[M x K] * BT[N x K]^T + bias). A,BT bf16 (row strides lda/ldb);
// fp32 acc. Tile 128x128x32; 256 threads = 4 waves, each 64x64.
// Double-buffered LDS + single barrier per iter; XOR-swizzled staging.
// XCD-aware bijective block swizzle (T1): all launch grids here are %8==0.
// EPI: 0 = bias + exact GELU -> bf16 Cb
//      1 = bias -> bf16 Cb only where idx[row] == match
//      2 = folded-LN epilogue:
//          Cf = (rs*acc + c0b2[col] - rsmu*c1[col]) * wm + adaptive_sel*(1-wm)
// ---------------------------------------------------------------------------
template <int EPI>
__global__ __launch_bounds__(256) void gemm_bt(
    const unsigned short* __restrict__ A, int lda,
    const unsigned short* __restrict__ BT, int ldb,
    const float* __restrict__ bias, unsigned short* __restrict__ Cb,
    float* __restrict__ Cf, int M, int N, int K,
    const int* __restrict__ idx, int match,
    const float* __restrict__ wm,
    const unsigned short* __restrict__ adaptive,
    const unsigned short* __restrict__ xn,
    const float* __restrict__ c1v,
    const float* __restrict__ rstat) {
    __shared__ __align__(16) unsigned short As[2][128 * 32];
    __shared__ __align__(16) unsigned short Bs[2][128 * 32];

    const int t = threadIdx.x;

    // XCD-aware bijective remap of the flattened block id (m157/m204).
    int id = blockIdx.y * gridDim.x + blockIdx.x;
    const int nwg = gridDim.x * gridDim.y;
    if ((nwg & 7) == 0) {
        const int cpx = nwg >> 3;
        id = (id & 7) * cpx + (id >> 3);
    }
    const int bx = id % gridDim.x;
    const int by = id / gridDim.x;
    const int m0 = by * 128;
    const int n0 = bx * 128;

    const int lane = t & 63;
    const int wid = t >> 6;

    // staging: lane i covers LDS rel-row i/4, chunk i%4; source column-chunk
    // is XOR-swizzled by row so readers land conflict-light.
    const int srow = lane >> 2;
    const int sch  = (lane & 3) ^ (srow & 3);   // source chunk (global col/8)
    const int scol = sch << 3;

    const int wr = (wid >> 1) << 6;
    const int wc = (wid & 1) << 6;
    const int ml = lane & 15;
    const int q = lane >> 4;
    const int qsw = ((q ^ (ml & 3)) << 3);      // swizzled LDS element offset

    f32x4 acc[4][4];
#pragma unroll
    for (int i = 0; i < 4; ++i)
#pragma unroll
        for (int j = 0; j < 4; ++j)
#pragma unroll
            for (int r = 0; r < 4; ++r) acc[i][j][r] = 0.0f;

    const int nk = K >> 5;

#define STAGE(KT, BUF)                                                          \
    {                                                                           \
        _Pragma("unroll")                                                       \
        for (int hh = 0; hh < 2; ++hh) {                                        \
            int rbase = wid * 32 + hh * 16;                                     \
            int row = rbase + srow;                                             \
            ld_lds16(A  + (size_t)(m0 + row) * lda + (KT) * 32 + scol,          \
                     &As[BUF][rbase * 32]);                                     \
            ld_lds16(BT + (size_t)(n0 + row) * ldb + (KT) * 32 + scol,          \
                     &Bs[BUF][rbase * 32]);                                     \
        }                                                                       \
    }

    STAGE(0, 0);
    for (int kt = 0; kt < nk; ++kt) {
        const int cur = kt & 1;
        __syncthreads();                 // drains DMA(kt) (in flight since kt-1)
        if (kt + 1 < nk) STAGE(kt + 1, cur ^ 1);

        bf16x8 af[4], bf[4];
#pragma unroll
        for (int i = 0; i < 4; ++i)
            af[i] = *(const bf16x8*)(&As[cur][(wr + i * 16 + ml) * 32 + qsw]);
#pragma unroll
        for (int j = 0; j < 4; ++j)
            bf[j] = *(const bf16x8*)(&Bs[cur][(wc + j * 16 + ml) * 32 + qsw]);
#pragma unroll
        for (int i = 0; i < 4; ++i)
#pragma unroll
            for (int j = 0; j < 4; ++j)
                acc[i][j] = __builtin_amdgcn_mfma_f32_16x16x32_bf16(af[i], bf[j], acc[i][j], 0, 0, 0);
    }
#undef STAGE

    // C/D layout: col = lane&15, row = quad*4 + reg  [m89/m91-verified]
#pragma unroll
    for (int i = 0; i < 4; ++i) {
        float rsv[4], rmv[4], wv[4];
        int idv[4];
        if (EPI == 1 || EPI == 2) {
#pragma unroll
            for (int r = 0; r < 4; ++r) {
                int row = m0 + wr + i * 16 + q * 4 + r;
                idv[r] = idx[row];
                if (EPI == 2) {
                    wv[r] = wm[row];
                    rsv[r] = rstat[2 * (size_t)row];
                    rmv[r] = rstat[2 * (size_t)row + 1];
                }
            }
        }
#pragma unroll
        for (int j = 0; j < 4; ++j) {
            int col = n0 + wc + j * 16 + ml;
            float bv = bias[col];
            float c1c = (EPI == 2) ? c1v[col] : 0.0f;
#pragma unroll
            for (int r = 0; r < 4; ++r) {
                int row = m0 + wr + i * 16 + q * 4 + r;
                size_t off = (size_t)row * N + col;
                if (EPI == 0) {
                    Cb[off] = f2b(gelu_exact(acc[i][j][r] + bv));
                } else if (EPI == 1) {
                    if (idv[r] == match) Cb[off] = f2b(acc[i][j][r] + bv);
                } else {
                    float bval = rsv[r] * acc[i][j][r] + bv - rmv[r] * c1c;
                    float a = b2f((idv[r] <= 1) ? adaptive[off] : xn[off]);
                    Cf[off] = bval * wv[r] + a * (1.0f - wv[r]);
                }
            }
        }
    }
}

// ---------------------------------------------------------------------------
extern "C" void kernel_launch(void* const* d_in, const int* in_sizes, int n_in,
                              void* d_out, int out_size, void* d_ws, size_t ws_size,
                              hipStream_t stream) {
    const float* x       = (const float*)d_in[0];
    const float* wm      = (const float*)d_in[1];
    const int*   widx    = (const int*)d_in[2];
    const float* ln_in_g = (const float*)d_in[3];
    const float* ln_in_b = (const float*)d_in[4];
    const float* W1      = (const float*)d_in[5];
    const float* b1      = (const float*)d_in[6];
    const float* ln_h_g  = (const float*)d_in[7];
    const float* ln_h_b  = (const float*)d_in[8];
    const float* W2      = (const float*)d_in[9];
    const float* b2      = (const float*)d_in[10];
    const float* a256_w1 = (const float*)d_in[11];
    const float* a256_b1 = (const float*)d_in[12];
    const float* a256_w2 = (const float*)d_in[13];
    const float* a256_b2 = (const float*)d_in[14];
    const float* a512_w1 = (const float*)d_in[15];
    const float* a512_b1 = (const float*)d_in[16];
    const float* a512_w2 = (const float*)d_in[17];
    const float* a512_b2 = (const float*)d_in[18];
    float* out = (float*)d_out;

    const int T = 8192, H = 1024, F = 4096;

    unsigned short* ws0   = (unsigned short*)d_ws;
    unsigned short* xn    = ws0;                       // T*H      bf16
    unsigned short* h     = xn    + (size_t)T * H;     // T*F      bf16
    unsigned short* tt    = h     + (size_t)T * F;     // T*768    bf16 (adapter ups, concat)
    unsigned short* adp   = tt    + (size_t)T * 768;   // T*H      bf16
    unsigned short* W1T   = adp   + (size_t)T * H;     // F*H      bf16
    unsigned short* W2T   = W1T   + (size_t)H * F;     // H*F      bf16 (pre-scaled by ln_h_g)
    unsigned short* awup  = W2T   + (size_t)F * H;     // 768*1024 bf16 (a256_w1^T ; a512_w1^T)
    unsigned short* aw2T0 = awup  + (size_t)768 * H;   // 1024*256 bf16
    unsigned short* aw2T1 = aw2T0 + (size_t)H * 256;   // 1024*512 bf16
    float*          ab1   = (float*)(aw2T1 + (size_t)H * 512);  // 768 fp32
    float*          stats = ab1 + 768;                 // T*2 fp32: rs, rs*mu
    float*          c0b2  = stats + (size_t)T * 2;     // H fp32: b.W2 + b2
    float*          c1    = c0b2 + H;                  // H fp32: g.W2

    dim3 tb(32, 8);
    // LN-fold prep: W2T = (diag(g) W2)^T; c0b2 = b.W2 + b2; c1 = g.W2
    init_c01<<<H / 256, 256, 0, stream>>>(b2, c0b2, c1);
    prep_c01<<<dim3(H / 256, F / 256), 256, 0, stream>>>(W2, ln_h_g, ln_h_b, c0b2, c1, F, H);

    transpose_f32_bf16<<<dim3(F / 32,   H / 32), tb, 0, stream>>>(W1, W1T, H, F, nullptr);
    transpose_f32_bf16<<<dim3(H / 32,   F / 32), tb, 0, stream>>>(W2, W2T, F, H, ln_h_g);
    transpose_f32_bf16<<<dim3(256 / 32, H / 32), tb, 0, stream>>>(a256_w1, awup, H, 256, nullptr);
    transpose_f32_bf16<<<dim3(512 / 32, H / 32), tb, 0, stream>>>(a512_w1, awup + (size_t)256 * H, H, 512, nullptr);
    transpose_f32_bf16<<<dim3(H / 32, 256 / 32), tb, 0, stream>>>(a256_w2, aw2T0, 256, H, nullptr);
    transpose_f32_bf16<<<dim3(H / 32, 512 / 32), tb, 0, stream>>>(a512_w2, aw2T1, 512, H, nullptr);
    concat_bias<<<3, 256, 0, stream>>>(a256_b1, a512_b1, ab1);

    // x (fp32) -> x_norm (bf16), vectorized
    ln1024<<<T, 256, 0, stream>>>(x, xn, ln_in_g, ln_in_b);

    // base FFN up: h = gelu(xn @ W1 + b1)
    gemm_bt<0><<<dim3(F / 128, T / 128), 256, 0, stream>>>(
        xn, H, W1T, H, b1, h, nullptr, T, F, H, nullptr, 0, nullptr, nullptr, nullptr, nullptr, nullptr);

    // LN stats of h (read-only pass, no atomics): stats = {rs, rs*mu} per row
    rowstats4096<<<T, 256, 0, stream>>>(h, stats);

    // merged adapter ups: tt = gelu(xn @ [a256_w1 | a512_w1] + [b1|b1])
    gemm_bt<0><<<dim3(768 / 128, T / 128), 256, 0, stream>>>(
        xn, H, awup, H, ab1, tt, nullptr, T, 768, H, nullptr, 0, nullptr, nullptr, nullptr, nullptr, nullptr);

    // adapter downs (routed rows only)
    gemm_bt<1><<<dim3(H / 128, T / 128), 256, 0, stream>>>(
        tt, 768, aw2T0, 256, a256_b2, adp, nullptr, T, H, 256, widx, 0, nullptr, nullptr, nullptr, nullptr, nullptr);
    gemm_bt<1><<<dim3(H / 128, T / 128), 256, 0, stream>>>(
        tt + 256, 768, aw2T1, 512, a512_b2, adp, nullptr, T, H, 512, widx, 1, nullptr, nullptr, nullptr, nullptr, nullptr);

    // out = (rs*(h @ g.W2) + (b.W2 + b2) - rs*mu*c1) * wm + adaptive * (1 - wm)
    gemm_bt<2><<<dim3(H / 128, T / 128), 256, 0, stream>>>(
        h, F, W2T, F, c0b2, nullptr, out, T, H, F, widx, 0, wm, adp, xn, c1, stats);
}